// Round 8
// baseline (1981.521 us; speedup 1.0000x reference)
//
#include <hip/hip_runtime.h>

// NonLocalMeans: rgb (8,3,1024,1024) f32, search 11x11, patch 5x5, circular.
// out(p) = sum_s w(p,s)*rgb(p-s) / sum_s w(p,s),
// w(p,s) = exp(-sqrt(box5x5((y - y_shift)^2)) * inv_h)
//
// R8 = R7 (FIN pixels direct from global; only Y + A in LDS -> 15.9 KB,
// 8 blocks/CU) with R7's two measured defects fixed:
//  1. amdgpu_waves_per_eu(4,4) RESTORED -- it, not launch_bounds, was holding
//     VGPR at 60 in R5/R6. R7 dropped it -> VGPR 108 -> occupancy 23% ->
//     latency-bound (1046us). min=4 is a floor, not a cap: with VGPR<=64 and
//     15.9 KB LDS the HW can hold 8 blocks/CU.
//  2. Per-(YO,pass) plane POINTERS + immediate offsets (prw[-J]) instead of
//     per-load integer gi -> zero per-load VALU, J folds into the 13-bit imm.
//     Edge wrap handled by dedicated body instantiations: pass B wraps only
//     at bx0==0, pass A only at bx0==W-TILE.
// Rationale (R6/R7 post-mortems): LDS instruction throughput is the governor;
// moving FIN px reads (44 b128/thread/dy, ~40% of LDS cycles) to the idle
// VMEM/L1/L2 pipe cuts LDS to ~60% and doubles occupancy.
// Fences (sched_barrier(0)) keep schedule order = source order (R5 lesson).
// Same f32 values, same accumulation order as R6/R7 -> bit-identical output.

#define HW (1024 * 1024)
#define W 1024
#define MASK 1023

constexpr int TILE = 32;
constexpr int YREG = 46;    // TILE + 2*7 (shift 5 + patch 2)
constexpr int YPITCH = 48;
constexpr int CREG = 42;    // TILE + 2*5 (A-field tile)
// (1/3 channel mean) * inv_h*log2(e); inv_h = 1/(1+1e-6)
constexpr float K3 = 1.4426935981939074f / 3.0f;

#define SBAR() __builtin_amdgcn_sched_barrier(0)

// 5-tap cross-correlation; c0..c4 in scope at expansion site
#define CR5(W0,W1,W2,W3,W4) \
    fmaf(c4,(W4), fmaf(c3,(W3), fmaf(c2,(W2), fmaf(c1,(W1), c0*(W0)))))

// h_J = 5-tap correlation over ywp[10-J .. 14-J].
// Pass A: J=0..5 (ywp[5..14]); pass B: J=6..10 (ywp[0..8]).
#define ROW_HA(RR)                                                          \
    const float* ycp = &ldsY[yci + (RR) * YPITCH];                          \
    const float* ywp = &ldsY[ywi + (RR) * YPITCH];                          \
    const float c0=ycp[0],c1=ycp[1],c2=ycp[2],c3=ycp[3],c4=ycp[4];          \
    const float w5 =ywp[5], w6 =ywp[6], w7 =ywp[7], w8 =ywp[8], w9 =ywp[9]; \
    const float w10=ywp[10],w11=ywp[11],w12=ywp[12],w13=ywp[13],w14=ywp[14];\
    const float h0 = CR5(w10,w11,w12,w13,w14);                              \
    const float h1 = CR5(w9, w10,w11,w12,w13);                              \
    const float h2 = CR5(w8, w9, w10,w11,w12);                              \
    const float h3 = CR5(w7, w8, w9, w10,w11);                              \
    const float h4 = CR5(w6, w7, w8, w9, w10);                              \
    const float h5 = CR5(w5, w6, w7, w8, w9);

#define ROW_HB(RR)                                                          \
    const float* ycp = &ldsY[yci + (RR) * YPITCH];                          \
    const float* ywp = &ldsY[ywi + (RR) * YPITCH];                          \
    const float c0=ycp[0],c1=ycp[1],c2=ycp[2],c3=ycp[3],c4=ycp[4];          \
    const float w0 =ywp[0], w1 =ywp[1], w2 =ywp[2], w3 =ywp[3], w4 =ywp[4]; \
    const float w5 =ywp[5], w6 =ywp[6], w7 =ywp[7], w8 =ywp[8];             \
    const float h6  = CR5(w4, w5, w6, w7, w8);                              \
    const float h7  = CR5(w3, w4, w5, w6, w7);                              \
    const float h8  = CR5(w2, w3, w4, w5, w6);                              \
    const float h9  = CR5(w1, w2, w3, w4, w5);                              \
    const float h10 = CR5(w0, w1, w2, w3, w4);

// per-pass vertical partials, named scalars, block-scoped
#define VDECLA(VD) float VD##_0, VD##_1, VD##_2, VD##_3, VD##_4, VD##_5
#define VSETA(VD)  VD##_0 =h0; VD##_1 =h1; VD##_2 =h2;                      \
                   VD##_3 =h3; VD##_4 =h4; VD##_5 =h5
#define VADDA(VD)  VD##_0+=h0; VD##_1+=h1; VD##_2+=h2;                      \
                   VD##_3+=h3; VD##_4+=h4; VD##_5+=h5
#define VDECLB(VD) float VD##_6, VD##_7, VD##_8, VD##_9, VD##_10
#define VSETB(VD)  VD##_6 =h6; VD##_7 =h7; VD##_8 =h8;                      \
                   VD##_9 =h9; VD##_10=h10
#define VADDB(VD)  VD##_6+=h6; VD##_7+=h7; VD##_8+=h8;                      \
                   VD##_9+=h9; VD##_10+=h10

// common FIN tail: S = Ac + Aw - 2*cross; dist = sqrt(|S|); w = exp2(-dist)
#define FIN_TAIL(YO, VD, J)                                                 \
    const float aw = ldsA[ari - (J)];                                       \
    float s = fmaf(-2.0f, VD##_##J, acb + aw);                              \
    float dist = __builtin_amdgcn_sqrtf(__builtin_fabsf(s));                \
    float wgt  = __builtin_amdgcn_exp2f(-dist);                             \
    aR##YO = fmaf(wgt, pr, aR##YO);                                         \
    aG##YO = fmaf(wgt, pg, aG##YO);                                         \
    aB##YO = fmaf(wgt, pb, aB##YO);                                         \
    aW##YO += wgt;

// fast: plane pointers, J folds into the 13-bit signed load immediate
#define FIN1P(YO, VD, J) do {                                               \
    const float pr = prw[-(J)];                                             \
    const float pg = pgw[-(J)];                                             \
    const float pb = pbw[-(J)];                                             \
    FIN_TAIL(YO, VD, J)                                                     \
} while (0)

// edge: per-J x-wrap via & MASK
#define FIN1E(YO, VD, J) do {                                               \
    const int gi = rowo + ((txo - (J)) & MASK);                             \
    const float pr = gr[gi];                                                \
    const float pg = gg[gi];                                                \
    const float pb = gb[gi];                                                \
    FIN_TAIL(YO, VD, J)                                                     \
} while (0)

#define FIN_HEADG(YO)                                                       \
    const int rowo = ((by0 + y0 + (YO) - dy) & MASK) << 10;                 \
    const int ari  = cri + (YO) * CREG;                                     \
    const float acb = ldsA[abi + (YO) * CREG];                              \
    const int gbase = rowo + txo;                                           \
    const float* prw = gr + gbase;                                          \
    const float* pgw = gg + gbase;                                          \
    const float* pbw = gb + gbase;                                          \
    (void)prw; (void)pgw; (void)pbw;

#define FIN_AF(YO, VD) do { FIN_HEADG(YO)                                   \
    FIN1P(YO,VD,0); FIN1P(YO,VD,1); FIN1P(YO,VD,2); SBAR();                 \
    FIN1P(YO,VD,3); FIN1P(YO,VD,4); FIN1P(YO,VD,5);                         \
} while (0)

#define FIN_BF(YO, VD) do { FIN_HEADG(YO)                                   \
    FIN1P(YO,VD,6); FIN1P(YO,VD,7); FIN1P(YO,VD,8); SBAR();                 \
    FIN1P(YO,VD,9); FIN1P(YO,VD,10);                                        \
} while (0)

#define FIN_AE(YO, VD) do { FIN_HEADG(YO)                                   \
    FIN1E(YO,VD,0); FIN1E(YO,VD,1); FIN1E(YO,VD,2); SBAR();                 \
    FIN1E(YO,VD,3); FIN1E(YO,VD,4); FIN1E(YO,VD,5);                         \
} while (0)

#define FIN_BE(YO, VD) do { FIN_HEADG(YO)                                   \
    FIN1E(YO,VD,6); FIN1E(YO,VD,7); FIN1E(YO,VD,8); SBAR();                 \
    FIN1E(YO,VD,9); FIN1E(YO,VD,10);                                        \
} while (0)

#define STORE(YO) do {                                                      \
    const int off = (by0 + y0 + (YO)) * W + bx0 + tx;                       \
    const float inv = 1.0f / aW##YO;                                        \
    obase[off]          = aR##YO * inv;                                     \
    obase[off + HW]     = aG##YO * inv;                                     \
    obase[off + 2 * HW] = aB##YO * inv;                                     \
} while (0)

// squared 5-tap row sum for the A-field precompute (y pre-scaled by K)
#define A5(p) fmaf((p)[4],(p)[4], fmaf((p)[3],(p)[3], fmaf((p)[2],(p)[2],   \
              fmaf((p)[1],(p)[1], (p)[0]*(p)[0]))))

// the dy loop, parameterized by FIN macro pair
#define DY_BODY(FINAM, FINBM)                                               \
    _Pragma("clang loop unroll(disable)")                                   \
    for (int dy = -5; dy <= 5; ++dy) {                                      \
        const int ywi = (y0 + 5 - dy) * YPITCH + tx;                        \
        const int cri = (y0 - dy + 5) * CREG + tx + 10;                     \
        {   /* pass A: J = 0..5 (dx = -5..0) */                             \
            VDECLA(v0); VDECLA(v1); VDECLA(v2); VDECLA(v3);                 \
            { ROW_HA(0); VSETA(v0); }                          SBAR();      \
            { ROW_HA(1); VADDA(v0); VSETA(v1); }               SBAR();      \
            { ROW_HA(2); VADDA(v0); VADDA(v1); VSETA(v2); }    SBAR();      \
            { ROW_HA(3); VADDA(v0); VADDA(v1); VADDA(v2); VSETA(v3); } SBAR(); \
            { ROW_HA(4); VADDA(v0); VADDA(v1); VADDA(v2); VADDA(v3); } SBAR(); \
            FINAM(0, v0);                                      SBAR();      \
            { ROW_HA(5); VADDA(v1); VADDA(v2); VADDA(v3); }    SBAR();      \
            FINAM(1, v1);                                      SBAR();      \
            { ROW_HA(6); VADDA(v2); VADDA(v3); }               SBAR();      \
            FINAM(2, v2);                                      SBAR();      \
            { ROW_HA(7); VADDA(v3); }                          SBAR();      \
            FINAM(3, v3);                                      SBAR();      \
        }                                                                   \
        {   /* pass B: J = 6..10 (dx = 1..5) */                             \
            VDECLB(v0); VDECLB(v1); VDECLB(v2); VDECLB(v3);                 \
            { ROW_HB(0); VSETB(v0); }                          SBAR();      \
            { ROW_HB(1); VADDB(v0); VSETB(v1); }               SBAR();      \
            { ROW_HB(2); VADDB(v0); VADDB(v1); VSETB(v2); }    SBAR();      \
            { ROW_HB(3); VADDB(v0); VADDB(v1); VADDB(v2); VSETB(v3); } SBAR(); \
            { ROW_HB(4); VADDB(v0); VADDB(v1); VADDB(v2); VADDB(v3); } SBAR(); \
            FINBM(0, v0);                                      SBAR();      \
            { ROW_HB(5); VADDB(v1); VADDB(v2); VADDB(v3); }    SBAR();      \
            FINBM(1, v1);                                      SBAR();      \
            { ROW_HB(6); VADDB(v2); VADDB(v3); }               SBAR();      \
            FINBM(2, v2);                                      SBAR();      \
            { ROW_HB(7); VADDB(v3); }                          SBAR();      \
            FINBM(3, v3);                                      SBAR();      \
        }                                                                   \
    }

__global__ void __launch_bounds__(256) __attribute__((amdgpu_waves_per_eu(4, 4)))
nlm_fused(const float* __restrict__ rgb, float* __restrict__ out) {
    __shared__ float ldsY[YREG * YPITCH];   // 8832 B (K-scaled luminance)
    __shared__ float ldsA[CREG * CREG];     // 7056 B (K^2 * box5x5(y^2))
                                            // total 15888 B -> 8 blocks/CU

    const int tid = threadIdx.x;
    const int batch = blockIdx.z;
    const int by0 = blockIdx.y * TILE;
    const int bx0 = blockIdx.x * TILE;

    const float* gr = rgb + (size_t)batch * 3 * HW;   // plane bases (uniform)
    const float* gg = gr + HW;
    const float* gb = gr + 2 * HW;

    // ---- stage K-scaled luminance tile (mean over channels), halo 7 ----
    for (int i = tid; i < YREG * YREG; i += 256) {
        int ry = i / YREG, rx = i - ry * YREG;
        int gy = (by0 + ry - 7) & MASK;
        int gx = (bx0 + rx - 7) & MASK;
        int off = gy * W + gx;
        float v = (gr[off] + gg[off] + gb[off]) * K3;
        ldsY[ry * YPITCH + rx] = v;
    }
    __syncthreads();    // Y complete before A-field compute

    // ---- A = K^2 * box5x5(y^2) over the 42x42 (halo 5) region ----
    for (int i = tid; i < CREG * CREG; i += 256) {
        int ry = i / CREG, rx = i - ry * CREG;
        const float* yb = &ldsY[ry * YPITCH + rx];   // A window = Y rows ry..ry+4
        float a =  A5(yb);
        a += A5(yb + YPITCH);
        a += A5(yb + 2 * YPITCH);
        a += A5(yb + 3 * YPITCH);
        a += A5(yb + 4 * YPITCH);
        ldsA[i] = a;
    }
    __syncthreads();

    const int tx = tid & 31;          // output column within tile
    const int y0 = (tid >> 5) * 4;    // 4-pixel column run per thread

    // loop-invariant scalar indices
    const int yci = (y0 + 5) * YPITCH + tx + 5;   // center rows, +RR*YPITCH
    const int abi = (y0 + 5) * CREG + tx + 5;     // A(center),  +YO*CREG
    const int txo = bx0 + tx + 5;                 // global col base, -J

    float aR0=0.f, aG0=0.f, aB0=0.f, aW0=0.f;
    float aR1=0.f, aG1=0.f, aB1=0.f, aW1=0.f;
    float aR2=0.f, aG2=0.f, aB2=0.f, aW2=0.f;
    float aR3=0.f, aG3=0.f, aB3=0.f, aW3=0.f;

    // x-wrap analysis: pass A touches cols txo-5..txo  (wraps only bx0==W-TILE)
    //                  pass B touches cols txo-10..txo-6 (wraps only bx0==0)
    if (bx0 == 0) {
        DY_BODY(FIN_AF, FIN_BE);
    } else if (bx0 == W - TILE) {
        DY_BODY(FIN_AE, FIN_BF);
    } else {
        DY_BODY(FIN_AF, FIN_BF);
    }

    float* obase = out + (size_t)batch * 3 * HW;
    STORE(0);
    STORE(1);
    STORE(2);
    STORE(3);
}

extern "C" void kernel_launch(void* const* d_in, const int* in_sizes, int n_in,
                              void* d_out, int out_size, void* d_ws, size_t ws_size,
                              hipStream_t stream) {
    const float* rgb = (const float*)d_in[0];
    float* out = (float*)d_out;
    dim3 grid(W / TILE, W / TILE, 8);
    dim3 block(256, 1, 1);
    hipLaunchKernelGGL(nlm_fused, grid, block, 0, stream, rgb, out);
}

// Round 9
// 876.001 us; speedup vs baseline: 2.2620x; 2.2620x over previous
//
#include <hip/hip_runtime.h>

// NonLocalMeans: rgb (8,3,1024,1024) f32, search 11x11, patch 5x5, circular.
// out(p) = sum_s w(p,s)*rgb(p-s) / sum_s w(p,s),
// w(p,s) = exp(-sqrt(box5x5((y - y_shift)^2)) * inv_h)
//
// R9 = R6 (all-LDS FIN, expand-the-square, dx-split, fences; 753us champion)
// re-geometried for FULL occupancy: 512-thread blocks, 2 output rows/thread.
// R8 post-mortem: R6 was ISSUE-STARVED, not BW-bound (LDS ~244us, VALU
// ~320us, trans ~103us per the 256 B/clk LDS model, wall 753us at 16
// waves/CU). Blocks/CU is LDS-limited at 4 either way (37 KB), so 512-thr
// blocks give 4x8 = 32 waves/CU (100%) -- double the TLP to fill the
// fence-serialization gaps. Per-thread ladder shrinks to 2 rows (6 patch
// rows), live set ~50 regs < R6's ~58: no new spill risk. The global-FIN
// detour (R7/R8) is abandoned: both variants broke the register budget.
// Accumulation order per accumulator unchanged (dy asc; J 0..5 then 6..10)
// -> bit-identical output to R6.
// WRITE_SIZE is the spill-o-meter: 98304 KB = output only.

#define HW (1024 * 1024)
#define W 1024
#define MASK 1023

constexpr int TILE = 32;
constexpr int YREG = 46;    // TILE + 2*7 (shift 5 + patch 2)
constexpr int YPITCH = 48;
constexpr int CREG = 42;    // TILE + 2*5
// (1/3 channel mean) * inv_h*log2(e); inv_h = 1/(1+1e-6)
constexpr float K3 = 1.4426935981939074f / 3.0f;

#define SBAR() __builtin_amdgcn_sched_barrier(0)

// 5-tap cross-correlation; c0..c4 in scope at expansion site
#define CR5(W0,W1,W2,W3,W4) \
    fmaf(c4,(W4), fmaf(c3,(W3), fmaf(c2,(W2), fmaf(c1,(W1), c0*(W0)))))

// h_J = 5-tap correlation over ywp[10-J .. 14-J].
// Pass A: J=0..5 (ywp[5..14]); pass B: J=6..10 (ywp[0..8]).
#define ROW_HA(RR)                                                          \
    const float* ycp = &ldsY[yci + (RR) * YPITCH];                          \
    const float* ywp = &ldsY[ywi + (RR) * YPITCH];                          \
    const float c0=ycp[0],c1=ycp[1],c2=ycp[2],c3=ycp[3],c4=ycp[4];          \
    const float w5 =ywp[5], w6 =ywp[6], w7 =ywp[7], w8 =ywp[8], w9 =ywp[9]; \
    const float w10=ywp[10],w11=ywp[11],w12=ywp[12],w13=ywp[13],w14=ywp[14];\
    const float h0 = CR5(w10,w11,w12,w13,w14);                              \
    const float h1 = CR5(w9, w10,w11,w12,w13);                              \
    const float h2 = CR5(w8, w9, w10,w11,w12);                              \
    const float h3 = CR5(w7, w8, w9, w10,w11);                              \
    const float h4 = CR5(w6, w7, w8, w9, w10);                              \
    const float h5 = CR5(w5, w6, w7, w8, w9);

#define ROW_HB(RR)                                                          \
    const float* ycp = &ldsY[yci + (RR) * YPITCH];                          \
    const float* ywp = &ldsY[ywi + (RR) * YPITCH];                          \
    const float c0=ycp[0],c1=ycp[1],c2=ycp[2],c3=ycp[3],c4=ycp[4];          \
    const float w0 =ywp[0], w1 =ywp[1], w2 =ywp[2], w3 =ywp[3], w4 =ywp[4]; \
    const float w5 =ywp[5], w6 =ywp[6], w7 =ywp[7], w8 =ywp[8];             \
    const float h6  = CR5(w4, w5, w6, w7, w8);                              \
    const float h7  = CR5(w3, w4, w5, w6, w7);                              \
    const float h8  = CR5(w2, w3, w4, w5, w6);                              \
    const float h9  = CR5(w1, w2, w3, w4, w5);                              \
    const float h10 = CR5(w0, w1, w2, w3, w4);

// per-pass vertical partials, named scalars, block-scoped
#define VDECLA(VD) float VD##_0, VD##_1, VD##_2, VD##_3, VD##_4, VD##_5
#define VSETA(VD)  VD##_0 =h0; VD##_1 =h1; VD##_2 =h2;                      \
                   VD##_3 =h3; VD##_4 =h4; VD##_5 =h5
#define VADDA(VD)  VD##_0+=h0; VD##_1+=h1; VD##_2+=h2;                      \
                   VD##_3+=h3; VD##_4+=h4; VD##_5+=h5
#define VDECLB(VD) float VD##_6, VD##_7, VD##_8, VD##_9, VD##_10
#define VSETB(VD)  VD##_6 =h6; VD##_7 =h7; VD##_8 =h8;                      \
                   VD##_9 =h9; VD##_10=h10
#define VADDB(VD)  VD##_6+=h6; VD##_7+=h7; VD##_8+=h8;                      \
                   VD##_9+=h9; VD##_10+=h10

// finalize one (YO,J): S = Ac + Aw - 2*cross (all pre-scaled by K^2),
// dist = sqrt(|S|), wgt = exp2(-dist); abs & neg are free modifiers.
#define FIN1(YO, VD, J) do {                                                \
    float4 px = crow[-(J)];                                                 \
    float s = fmaf(-2.0f, VD##_##J, acb + px.w);                            \
    float dist = __builtin_amdgcn_sqrtf(__builtin_fabsf(s));                \
    float wgt  = __builtin_amdgcn_exp2f(-dist);                             \
    aR##YO = fmaf(wgt, px.x, aR##YO);                                       \
    aG##YO = fmaf(wgt, px.y, aG##YO);                                       \
    aB##YO = fmaf(wgt, px.z, aB##YO);                                       \
    aW##YO += wgt;                                                          \
} while (0)

#define FIN_A(YO, VD) do {                                                  \
    const float4* crow = &ldsC[cri + (YO) * CREG];                          \
    const float acb = ldsC[abi + (YO) * CREG].w;                            \
    FIN1(YO,VD,0); FIN1(YO,VD,1); FIN1(YO,VD,2);                            \
    FIN1(YO,VD,3); FIN1(YO,VD,4); FIN1(YO,VD,5);                            \
} while (0)

#define FIN_B(YO, VD) do {                                                  \
    const float4* crow = &ldsC[cri + (YO) * CREG];                          \
    const float acb = ldsC[abi + (YO) * CREG].w;                            \
    FIN1(YO,VD,6); FIN1(YO,VD,7); FIN1(YO,VD,8);                            \
    FIN1(YO,VD,9); FIN1(YO,VD,10);                                          \
} while (0)

#define STORE(YO) do {                                                      \
    const int off = (by0 + y0 + (YO)) * W + bx0 + tx;                       \
    const float inv = 1.0f / aW##YO;                                        \
    obase[off]          = aR##YO * inv;                                     \
    obase[off + HW]     = aG##YO * inv;                                     \
    obase[off + 2 * HW] = aB##YO * inv;                                     \
} while (0)

// squared 5-tap row sum for the A-field precompute (y pre-scaled by K)
#define A5(p) fmaf((p)[4],(p)[4], fmaf((p)[3],(p)[3], fmaf((p)[2],(p)[2],   \
              fmaf((p)[1],(p)[1], (p)[0]*(p)[0]))))

__global__ void __launch_bounds__(512) __attribute__((amdgpu_waves_per_eu(4, 4)))
nlm_fused(const float* __restrict__ rgb, float* __restrict__ out) {
    __shared__ float  ldsY[YREG * YPITCH];      // 8832 B  (K-scaled luminance)
    __shared__ float4 ldsC[CREG * CREG];        // 28224 B (.w = K^2*box5x5(y^2))
                                                // 37 KB -> 4 blocks x 8 waves/CU

    const int tid = threadIdx.x;
    const int batch = blockIdx.z;
    const int by0 = blockIdx.y * TILE;
    const int bx0 = blockIdx.x * TILE;

    const float* base = rgb + (size_t)batch * 3 * HW;

    // ---- stage K-scaled luminance tile (mean over channels), halo 7 ----
    for (int i = tid; i < YREG * YREG; i += 512) {
        int ry = i / YREG, rx = i - ry * YREG;
        int gy = (by0 + ry - 7) & MASK;
        int gx = (bx0 + rx - 7) & MASK;
        int off = gy * W + gx;
        float v = (base[off] + base[off + HW] + base[off + 2 * HW]) * K3;
        ldsY[ry * YPITCH + rx] = v;
    }
    __syncthreads();    // Y complete before A-field compute

    // ---- stage rgb tile as float4 (halo 5), .w = K^2 * box5x5(y^2) ----
    for (int i = tid; i < CREG * CREG; i += 512) {
        int ry = i / CREG, rx = i - ry * CREG;
        int gy = (by0 + ry - 5) & MASK;
        int gx = (bx0 + rx - 5) & MASK;
        int off = gy * W + gx;
        const float* yb = &ldsY[ry * YPITCH + rx];   // A window = Y rows ry..ry+4
        float a =  A5(yb);
        a += A5(yb + YPITCH);
        a += A5(yb + 2 * YPITCH);
        a += A5(yb + 3 * YPITCH);
        a += A5(yb + 4 * YPITCH);
        ldsC[i] = make_float4(base[off], base[off + HW], base[off + 2 * HW], a);
    }
    __syncthreads();

    const int tx = tid & 31;          // output column within tile
    const int y0 = (tid >> 5) * 2;    // 2-pixel column run per thread (16 groups)

    // loop-invariant scalar LDS indices (offsets fold into ds_read imms)
    const int yci = (y0 + 5) * YPITCH + tx + 5;   // center rows, +RR*YPITCH
    const int abi = (y0 + 5) * CREG + tx + 5;     // A(center),  +YO*CREG

    float aR0=0.f, aG0=0.f, aB0=0.f, aW0=0.f;
    float aR1=0.f, aG1=0.f, aB1=0.f, aW1=0.f;

    #pragma clang loop unroll(disable)
    for (int dy = -5; dy <= 5; ++dy) {
        const int ywi = (y0 + 5 - dy) * YPITCH + tx;      // +RR*YPITCH
        const int cri = (y0 - dy + 5) * CREG + tx + 10;   // +YO*CREG - J
        {   // ---- pass A: J = 0..5 (dx = -5..0) ----
            VDECLA(v0); VDECLA(v1);
            { ROW_HA(0); VSETA(v0); }               SBAR();
            { ROW_HA(1); VADDA(v0); VSETA(v1); }    SBAR();
            { ROW_HA(2); VADDA(v0); VADDA(v1); }    SBAR();
            { ROW_HA(3); VADDA(v0); VADDA(v1); }    SBAR();
            { ROW_HA(4); VADDA(v0); VADDA(v1); }    SBAR();
            FIN_A(0, v0);                           SBAR();
            { ROW_HA(5); VADDA(v1); }               SBAR();
            FIN_A(1, v1);                           SBAR();
        }
        {   // ---- pass B: J = 6..10 (dx = 1..5) ----
            VDECLB(v0); VDECLB(v1);
            { ROW_HB(0); VSETB(v0); }               SBAR();
            { ROW_HB(1); VADDB(v0); VSETB(v1); }    SBAR();
            { ROW_HB(2); VADDB(v0); VADDB(v1); }    SBAR();
            { ROW_HB(3); VADDB(v0); VADDB(v1); }    SBAR();
            { ROW_HB(4); VADDB(v0); VADDB(v1); }    SBAR();
            FIN_B(0, v0);                           SBAR();
            { ROW_HB(5); VADDB(v1); }               SBAR();
            FIN_B(1, v1);                           SBAR();
        }
    }

    float* obase = out + (size_t)batch * 3 * HW;
    STORE(0);
    STORE(1);
}

extern "C" void kernel_launch(void* const* d_in, const int* in_sizes, int n_in,
                              void* d_out, int out_size, void* d_ws, size_t ws_size,
                              hipStream_t stream) {
    const float* rgb = (const float*)d_in[0];
    float* out = (float*)d_out;
    dim3 grid(W / TILE, W / TILE, 8);
    dim3 block(512, 1, 1);
    hipLaunchKernelGGL(nlm_fused, grid, block, 0, stream, rgb, out);
}

// Round 10
// 865.128 us; speedup vs baseline: 2.2904x; 1.0126x over previous
//
#include <hip/hip_runtime.h>

// NonLocalMeans: rgb (8,3,1024,1024) f32, search 11x11, patch 5x5, circular.
// out(p) = sum_s w(p,s)*rgb(p-s) / sum_s w(p,s),
// w(p,s) = exp(-sqrt(box5x5((y - y_shift)^2)) * inv_h)
//
// R10 = R9 with ONE change: amdgpu_waves_per_eu(4,4) -> (8,8).
// R9 post-mortem: the (4,4) attribute's max=4 CLAMPED residency at 4
// waves/EU = 16 waves/CU (measured occupancy 41%), negating the entire
// point of the 512-thread geometry. The hardware supports 32 waves/CU here:
// LDS 4 blocks x 37376 B = 146 KB <= 160 KB; VGPR 52 <= 64 (the 8-waves/SIMD
// budget). min=8 keeps the allocator at the 64-VGPR budget (live set proved
// 52, spill-free: WRITE_SIZE = 98304 = output only); max=8 lifts the cap.
// True VALU busy ~51% (derived 102% / 2, SIMD-32 vs gfx94x formula) => half
// the issue slots idle; doubling resident waves fills the fence gaps.
// Accumulation order unchanged (dy asc; J 0..5 then 6..10) -> bit-identical.

#define HW (1024 * 1024)
#define W 1024
#define MASK 1023

constexpr int TILE = 32;
constexpr int YREG = 46;    // TILE + 2*7 (shift 5 + patch 2)
constexpr int YPITCH = 48;
constexpr int CREG = 42;    // TILE + 2*5
// (1/3 channel mean) * inv_h*log2(e); inv_h = 1/(1+1e-6)
constexpr float K3 = 1.4426935981939074f / 3.0f;

#define SBAR() __builtin_amdgcn_sched_barrier(0)

// 5-tap cross-correlation; c0..c4 in scope at expansion site
#define CR5(W0,W1,W2,W3,W4) \
    fmaf(c4,(W4), fmaf(c3,(W3), fmaf(c2,(W2), fmaf(c1,(W1), c0*(W0)))))

// h_J = 5-tap correlation over ywp[10-J .. 14-J].
// Pass A: J=0..5 (ywp[5..14]); pass B: J=6..10 (ywp[0..8]).
#define ROW_HA(RR)                                                          \
    const float* ycp = &ldsY[yci + (RR) * YPITCH];                          \
    const float* ywp = &ldsY[ywi + (RR) * YPITCH];                          \
    const float c0=ycp[0],c1=ycp[1],c2=ycp[2],c3=ycp[3],c4=ycp[4];          \
    const float w5 =ywp[5], w6 =ywp[6], w7 =ywp[7], w8 =ywp[8], w9 =ywp[9]; \
    const float w10=ywp[10],w11=ywp[11],w12=ywp[12],w13=ywp[13],w14=ywp[14];\
    const float h0 = CR5(w10,w11,w12,w13,w14);                              \
    const float h1 = CR5(w9, w10,w11,w12,w13);                              \
    const float h2 = CR5(w8, w9, w10,w11,w12);                              \
    const float h3 = CR5(w7, w8, w9, w10,w11);                              \
    const float h4 = CR5(w6, w7, w8, w9, w10);                              \
    const float h5 = CR5(w5, w6, w7, w8, w9);

#define ROW_HB(RR)                                                          \
    const float* ycp = &ldsY[yci + (RR) * YPITCH];                          \
    const float* ywp = &ldsY[ywi + (RR) * YPITCH];                          \
    const float c0=ycp[0],c1=ycp[1],c2=ycp[2],c3=ycp[3],c4=ycp[4];          \
    const float w0 =ywp[0], w1 =ywp[1], w2 =ywp[2], w3 =ywp[3], w4 =ywp[4]; \
    const float w5 =ywp[5], w6 =ywp[6], w7 =ywp[7], w8 =ywp[8];             \
    const float h6  = CR5(w4, w5, w6, w7, w8);                              \
    const float h7  = CR5(w3, w4, w5, w6, w7);                              \
    const float h8  = CR5(w2, w3, w4, w5, w6);                              \
    const float h9  = CR5(w1, w2, w3, w4, w5);                              \
    const float h10 = CR5(w0, w1, w2, w3, w4);

// per-pass vertical partials, named scalars, block-scoped
#define VDECLA(VD) float VD##_0, VD##_1, VD##_2, VD##_3, VD##_4, VD##_5
#define VSETA(VD)  VD##_0 =h0; VD##_1 =h1; VD##_2 =h2;                      \
                   VD##_3 =h3; VD##_4 =h4; VD##_5 =h5
#define VADDA(VD)  VD##_0+=h0; VD##_1+=h1; VD##_2+=h2;                      \
                   VD##_3+=h3; VD##_4+=h4; VD##_5+=h5
#define VDECLB(VD) float VD##_6, VD##_7, VD##_8, VD##_9, VD##_10
#define VSETB(VD)  VD##_6 =h6; VD##_7 =h7; VD##_8 =h8;                      \
                   VD##_9 =h9; VD##_10=h10
#define VADDB(VD)  VD##_6+=h6; VD##_7+=h7; VD##_8+=h8;                      \
                   VD##_9+=h9; VD##_10+=h10

// finalize one (YO,J): S = Ac + Aw - 2*cross (all pre-scaled by K^2),
// dist = sqrt(|S|), wgt = exp2(-dist); abs & neg are free modifiers.
#define FIN1(YO, VD, J) do {                                                \
    float4 px = crow[-(J)];                                                 \
    float s = fmaf(-2.0f, VD##_##J, acb + px.w);                            \
    float dist = __builtin_amdgcn_sqrtf(__builtin_fabsf(s));                \
    float wgt  = __builtin_amdgcn_exp2f(-dist);                             \
    aR##YO = fmaf(wgt, px.x, aR##YO);                                       \
    aG##YO = fmaf(wgt, px.y, aG##YO);                                       \
    aB##YO = fmaf(wgt, px.z, aB##YO);                                       \
    aW##YO += wgt;                                                          \
} while (0)

#define FIN_A(YO, VD) do {                                                  \
    const float4* crow = &ldsC[cri + (YO) * CREG];                          \
    const float acb = ldsC[abi + (YO) * CREG].w;                            \
    FIN1(YO,VD,0); FIN1(YO,VD,1); FIN1(YO,VD,2);                            \
    FIN1(YO,VD,3); FIN1(YO,VD,4); FIN1(YO,VD,5);                            \
} while (0)

#define FIN_B(YO, VD) do {                                                  \
    const float4* crow = &ldsC[cri + (YO) * CREG];                          \
    const float acb = ldsC[abi + (YO) * CREG].w;                            \
    FIN1(YO,VD,6); FIN1(YO,VD,7); FIN1(YO,VD,8);                            \
    FIN1(YO,VD,9); FIN1(YO,VD,10);                                          \
} while (0)

#define STORE(YO) do {                                                      \
    const int off = (by0 + y0 + (YO)) * W + bx0 + tx;                       \
    const float inv = 1.0f / aW##YO;                                        \
    obase[off]          = aR##YO * inv;                                     \
    obase[off + HW]     = aG##YO * inv;                                     \
    obase[off + 2 * HW] = aB##YO * inv;                                     \
} while (0)

// squared 5-tap row sum for the A-field precompute (y pre-scaled by K)
#define A5(p) fmaf((p)[4],(p)[4], fmaf((p)[3],(p)[3], fmaf((p)[2],(p)[2],   \
              fmaf((p)[1],(p)[1], (p)[0]*(p)[0]))))

__global__ void __launch_bounds__(512) __attribute__((amdgpu_waves_per_eu(8, 8)))
nlm_fused(const float* __restrict__ rgb, float* __restrict__ out) {
    __shared__ float  ldsY[YREG * YPITCH];      // 8832 B  (K-scaled luminance)
    __shared__ float4 ldsC[CREG * CREG];        // 28224 B (.w = K^2*box5x5(y^2))
                                                // 37 KB -> 4 blocks x 8 waves/CU

    const int tid = threadIdx.x;
    const int batch = blockIdx.z;
    const int by0 = blockIdx.y * TILE;
    const int bx0 = blockIdx.x * TILE;

    const float* base = rgb + (size_t)batch * 3 * HW;

    // ---- stage K-scaled luminance tile (mean over channels), halo 7 ----
    for (int i = tid; i < YREG * YREG; i += 512) {
        int ry = i / YREG, rx = i - ry * YREG;
        int gy = (by0 + ry - 7) & MASK;
        int gx = (bx0 + rx - 7) & MASK;
        int off = gy * W + gx;
        float v = (base[off] + base[off + HW] + base[off + 2 * HW]) * K3;
        ldsY[ry * YPITCH + rx] = v;
    }
    __syncthreads();    // Y complete before A-field compute

    // ---- stage rgb tile as float4 (halo 5), .w = K^2 * box5x5(y^2) ----
    for (int i = tid; i < CREG * CREG; i += 512) {
        int ry = i / CREG, rx = i - ry * CREG;
        int gy = (by0 + ry - 5) & MASK;
        int gx = (bx0 + rx - 5) & MASK;
        int off = gy * W + gx;
        const float* yb = &ldsY[ry * YPITCH + rx];   // A window = Y rows ry..ry+4
        float a =  A5(yb);
        a += A5(yb + YPITCH);
        a += A5(yb + 2 * YPITCH);
        a += A5(yb + 3 * YPITCH);
        a += A5(yb + 4 * YPITCH);
        ldsC[i] = make_float4(base[off], base[off + HW], base[off + 2 * HW], a);
    }
    __syncthreads();

    const int tx = tid & 31;          // output column within tile
    const int y0 = (tid >> 5) * 2;    // 2-pixel column run per thread (16 groups)

    // loop-invariant scalar LDS indices (offsets fold into ds_read imms)
    const int yci = (y0 + 5) * YPITCH + tx + 5;   // center rows, +RR*YPITCH
    const int abi = (y0 + 5) * CREG + tx + 5;     // A(center),  +YO*CREG

    float aR0=0.f, aG0=0.f, aB0=0.f, aW0=0.f;
    float aR1=0.f, aG1=0.f, aB1=0.f, aW1=0.f;

    #pragma clang loop unroll(disable)
    for (int dy = -5; dy <= 5; ++dy) {
        const int ywi = (y0 + 5 - dy) * YPITCH + tx;      // +RR*YPITCH
        const int cri = (y0 - dy + 5) * CREG + tx + 10;   // +YO*CREG - J
        {   // ---- pass A: J = 0..5 (dx = -5..0) ----
            VDECLA(v0); VDECLA(v1);
            { ROW_HA(0); VSETA(v0); }               SBAR();
            { ROW_HA(1); VADDA(v0); VSETA(v1); }    SBAR();
            { ROW_HA(2); VADDA(v0); VADDA(v1); }    SBAR();
            { ROW_HA(3); VADDA(v0); VADDA(v1); }    SBAR();
            { ROW_HA(4); VADDA(v0); VADDA(v1); }    SBAR();
            FIN_A(0, v0);                           SBAR();
            { ROW_HA(5); VADDA(v1); }               SBAR();
            FIN_A(1, v1);                           SBAR();
        }
        {   // ---- pass B: J = 6..10 (dx = 1..5) ----
            VDECLB(v0); VDECLB(v1);
            { ROW_HB(0); VSETB(v0); }               SBAR();
            { ROW_HB(1); VADDB(v0); VSETB(v1); }    SBAR();
            { ROW_HB(2); VADDB(v0); VADDB(v1); }    SBAR();
            { ROW_HB(3); VADDB(v0); VADDB(v1); }    SBAR();
            { ROW_HB(4); VADDB(v0); VADDB(v1); }    SBAR();
            FIN_B(0, v0);                           SBAR();
            { ROW_HB(5); VADDB(v1); }               SBAR();
            FIN_B(1, v1);                           SBAR();
        }
    }

    float* obase = out + (size_t)batch * 3 * HW;
    STORE(0);
    STORE(1);
}

extern "C" void kernel_launch(void* const* d_in, const int* in_sizes, int n_in,
                              void* d_out, int out_size, void* d_ws, size_t ws_size,
                              hipStream_t stream) {
    const float* rgb = (const float*)d_in[0];
    float* out = (float*)d_out;
    dim3 grid(W / TILE, W / TILE, 8);
    dim3 block(512, 1, 1);
    hipLaunchKernelGGL(nlm_fused, grid, block, 0, stream, rgb, out);
}